// Round 12
// baseline (21.669 us; speedup 1.0000x reference)
//
#include <hip/hip_runtime.h>

#define B_ROWS   32768
#define NUM_CLS  1000
#define FEAT     512

#define INTER_BLOCKS    16
#define INTRA_BLOCKS    1024
#define THREADS         256
#define WAVES_PER_BLOCK 4
#define ROWS_PER_WAVE   8      // 1024 * 4 * 8 = 32768
#define TOTAL_WAVES     (INTRA_BLOCKS * WAVES_PER_BLOCK)   // 4096
#define LABELS_PER_IB   (B_ROWS / INTER_BLOCKS)            // 2048
#define LISTCAP         128

typedef float f32x4 __attribute__((ext_vector_type(4)));
typedef float f32x2 __attribute__((ext_vector_type(2)));

// ws layout (floats) — every slot written unconditionally every call, no zeroing:
//   [0 .. 4096)                 per-WAVE intra partials
//   [4096 .. 4096+16*1032)      inter per-block slots:
//       slot+0 = cnt0, slot+1 = cnt1, slot+[2..514) = sum0, slot+[514..1026) = sum1
#define WS_INTER 4096
#define SLOT     1032

// issue feature+center loads for rows ROW, ROW+1 into 8 named f32x4 regs
#define LOADPAIR(ROW, FA,FB,FC,FD, CA,CB,CC,CD) do {                         \
    const int _lab0 = labels[(ROW)];                                         \
    const int _lab1 = labels[(ROW) + 1];                                     \
    const f32x4* _f0 = (const f32x4*)(features + (size_t)(ROW) * FEAT);      \
    const f32x4* _f1 = (const f32x4*)(features + (size_t)((ROW)+1) * FEAT);  \
    const f32x4* _c0 = (const f32x4*)(center + (size_t)_lab0 * FEAT);        \
    const f32x4* _c1 = (const f32x4*)(center + (size_t)_lab1 * FEAT);        \
    FA = _f0[lane]; FB = _f0[lane + 64];                                     \
    FC = _f1[lane]; FD = _f1[lane + 64];                                     \
    CA = _c0[lane]; CB = _c0[lane + 64];                                     \
    CC = _c1[lane]; CD = _c1[lane + 64];                                     \
} while (0)

// reduce a 2-row stage to the pair's distance sum (uniform across lanes)
#define REDUCE2(FA,FB,FC,FD, CA,CB,CC,CD) ({                                 \
    f32x4 _d0 = FA - CA, _d1 = FB - CB, _d2 = FC - CC, _d3 = FD - CD;        \
    float _p0 = _d0.x*_d0.x + _d0.y*_d0.y + _d0.z*_d0.z + _d0.w*_d0.w        \
              + _d1.x*_d1.x + _d1.y*_d1.y + _d1.z*_d1.z + _d1.w*_d1.w;       \
    float _p1 = _d2.x*_d2.x + _d2.y*_d2.y + _d2.z*_d2.z + _d2.w*_d2.w        \
              + _d3.x*_d3.x + _d3.y*_d3.y + _d3.z*_d3.z + _d3.w*_d3.w;       \
    const bool _b0 = lane & 1;                                               \
    float _send = _b0 ? _p0 : _p1;                                           \
    float _keep = _b0 ? _p1 : _p0;                                           \
    float _u = _keep + __shfl_xor(_send, 1);                                 \
    _u += __shfl_xor(_u, 2);                                                 \
    _u += __shfl_xor(_u, 4);                                                 \
    _u += __shfl_xor(_u, 8);                                                 \
    _u += __shfl_xor(_u, 16);                                                \
    _u += __shfl_xor(_u, 32);                                                \
    float _dist = sqrtf(_u);                                                 \
    _dist = fminf(fmaxf(_dist, 1e-12f), 1e12f);                              \
    _dist + __shfl_xor(_dist, 1);                                            \
})

__global__ __launch_bounds__(THREADS, 4) void loss_pass1(
    const float* __restrict__ features,
    const int*   __restrict__ labels,
    const float* __restrict__ center,
    float*       __restrict__ ws)
{
    if (blockIdx.x < INTER_BLOCKS) {
        // ================= inter blocks: class C-2/C-1 partial sums =================
        const int ib = blockIdx.x;
        const int t  = threadIdx.x;

        __shared__ int list[LISTCAP];
        __shared__ int nm_s;
        if (t == 0) nm_s = 0;
        __syncthreads();

        const int4* lab4 = (const int4*)(labels + ib * LABELS_PER_IB);
        #pragma unroll
        for (int k = 0; k < 2; ++k) {
            const int j = t + k * 256;
            int4 L = lab4[j];
            const int row0 = ib * LABELS_PER_IB + 4 * j;
            if (L.x >= NUM_CLS - 2) { int i = atomicAdd(&nm_s, 1); if (i < LISTCAP) list[i] = (row0 << 1)       | (L.x - (NUM_CLS - 2)); }
            if (L.y >= NUM_CLS - 2) { int i = atomicAdd(&nm_s, 1); if (i < LISTCAP) list[i] = ((row0 + 1) << 1) | (L.y - (NUM_CLS - 2)); }
            if (L.z >= NUM_CLS - 2) { int i = atomicAdd(&nm_s, 1); if (i < LISTCAP) list[i] = ((row0 + 2) << 1) | (L.z - (NUM_CLS - 2)); }
            if (L.w >= NUM_CLS - 2) { int i = atomicAdd(&nm_s, 1); if (i < LISTCAP) list[i] = ((row0 + 3) << 1) | (L.w - (NUM_CLS - 2)); }
        }
        __syncthreads();
        const int nm = min(nm_s, LISTCAP);

        float s0a = 0.0f, s0b = 0.0f, s1a = 0.0f, s1b = 0.0f;
        int c0 = 0, c1 = 0;
        for (int m = 0; m < nm; ++m) {
            const int e   = list[m];
            const int row = e >> 1;
            const f32x2 v = ((const f32x2*)(features + (size_t)row * FEAT))[t];
            if (e & 1) { s1a += v.x; s1b += v.y; ++c1; }
            else       { s0a += v.x; s0b += v.y; ++c0; }
        }

        float* slot = ws + WS_INTER + ib * SLOT;
        if (t == 0) { slot[0] = (float)c0; slot[1] = (float)c1; }
        f32x2 v0; v0.x = s0a; v0.y = s0b;
        f32x2 v1; v1.x = s1a; v1.y = s1b;
        ((f32x2*)(slot + 2))[t]   = v0;
        ((f32x2*)(slot + 514))[t] = v1;
        return;
    }

    // ===== intra blocks: persistent waves, 8 rows each, 2-deep pipelined =====
    const int bid  = blockIdx.x - INTER_BLOCKS;
    const int lane = threadIdx.x & 63;
    const int wave = __builtin_amdgcn_readfirstlane(threadIdx.x >> 6);
    const int wid  = bid * WAVES_PER_BLOCK + wave;
    const int base_row = wid * ROWS_PER_WAVE;

    f32x4 fa0, fb0, fc0, fd0, ca0, cb0, cc0, cd0;   // stage buffer A
    f32x4 fa1, fb1, fc1, fd1, ca1, cb1, cc1, cd1;   // stage buffer B

    float acc;

    LOADPAIR(base_row,     fa0, fb0, fc0, fd0, ca0, cb0, cc0, cd0);  // stage 0
    LOADPAIR(base_row + 2, fa1, fb1, fc1, fd1, ca1, cb1, cc1, cd1);  // prefetch stage 1
    acc  = REDUCE2(fa0, fb0, fc0, fd0, ca0, cb0, cc0, cd0);          // stage 0 compute
    LOADPAIR(base_row + 4, fa0, fb0, fc0, fd0, ca0, cb0, cc0, cd0);  // prefetch stage 2
    acc += REDUCE2(fa1, fb1, fc1, fd1, ca1, cb1, cc1, cd1);          // stage 1 compute
    LOADPAIR(base_row + 6, fa1, fb1, fc1, fd1, ca1, cb1, cc1, cd1);  // prefetch stage 3
    acc += REDUCE2(fa0, fb0, fc0, fd0, ca0, cb0, cc0, cd0);          // stage 2 compute
    acc += REDUCE2(fa1, fb1, fc1, fd1, ca1, cb1, cc1, cd1);          // stage 3 compute

    if (lane == 0)
        ws[wid] = acc;    // unique per-wave slot: no LDS, no barrier, no atomic
}

__global__ __launch_bounds__(512) void loss_pass2(
    const float* __restrict__ center,
    const float* __restrict__ ws,
    float*       __restrict__ out)
{
    const int t = threadIdx.x;     // 512 threads, 8 waves

    float cnt0 = 0.0f, cnt1 = 0.0f;
    #pragma unroll
    for (int b = 0; b < INTER_BLOCKS; ++b) {
        const float* slot = ws + WS_INTER + b * SLOT;
        cnt0 += slot[0];
        cnt1 += slot[1];
    }
    cnt0 = fmaxf(cnt0, 1.0f);
    cnt1 = fmaxf(cnt1, 1.0f);

    float s0 = 0.0f, s1 = 0.0f;
    #pragma unroll
    for (int b = 0; b < INTER_BLOCKS; ++b) {
        const float* slot = ws + WS_INTER + b * SLOT;
        s0 += slot[2 + t];
        s1 += slot[514 + t];
    }

    float a  = (center[(size_t)(NUM_CLS - 2) * FEAT + t] + s0) / cnt0;
    float bb = (center[(size_t)(NUM_CLS - 1) * FEAT + t] + s1) / cnt1;
    float df = a - bb;
    float p_inter = df * df;

    // intra: 4096 wave partials, f32x4 x 2 per thread
    const f32x4* part4 = (const f32x4*)ws;
    float p_intra = 0.0f;
    #pragma unroll
    for (int k = 0; k < 2; ++k) {
        f32x4 v = part4[t + k * 512];
        p_intra += (v.x + v.y) + (v.z + v.w);
    }

    #pragma unroll
    for (int off = 32; off; off >>= 1) {
        p_inter += __shfl_xor(p_inter, off);
        p_intra += __shfl_xor(p_intra, off);
    }

    __shared__ float si[8], sa[8];
    if ((t & 63) == 0) { si[t >> 6] = p_inter; sa[t >> 6] = p_intra; }
    __syncthreads();

    if (t == 0) {
        float s_inter = 0.0f, s_intra = 0.0f;
        #pragma unroll
        for (int i = 0; i < 8; ++i) { s_inter += si[i]; s_intra += sa[i]; }
        float d_last = sqrtf(s_inter);
        out[0] = s_intra * (1.0f / (float)B_ROWS);
        out[1] = (2.0f / d_last) * (1.0f / ((float)NUM_CLS * (float)(NUM_CLS - 1)));
    }
}

extern "C" void kernel_launch(void* const* d_in, const int* in_sizes, int n_in,
                              void* d_out, int out_size, void* d_ws, size_t ws_size,
                              hipStream_t stream) {
    const float* features = (const float*)d_in[0];
    const int*   labels   = (const int*)d_in[1];
    const float* center   = (const float*)d_in[2];
    float* out = (float*)d_out;
    float* ws  = (float*)d_ws;

    loss_pass1<<<INTER_BLOCKS + INTRA_BLOCKS, THREADS, 0, stream>>>(features, labels, center, ws);
    loss_pass2<<<1, 512, 0, stream>>>(center, ws, out);
}